// Round 1
// baseline (114.755 us; speedup 1.0000x reference)
//
#include <hip/hip_runtime.h>

// Quantizer forward: out = hard_q = nearest of 25 uniform levels in [-1, 1].
// (soft_q + stop_grad(hard_q - soft_q) has forward value == hard_q up to
//  ~1e-8 float rounding, far below the 2e-2 absmax threshold.)
//
// Correctness-critical: must match numpy's argmin over fl((x - levels[l])^2)
// with first-tie-wins. We pick a rounded candidate c, then re-decide among
// {c-1, c, c+1} using bit-exact numpy float32 arithmetic.
//
// R1: streaming-efficiency pass. Kernel is memory-bound (134 MB traffic,
// floor ~21.3 us @6.3 TB/s; previous implied ~26 us). Changes:
//  - 8 independent float4 loads in flight per thread (UNROLL=8, 2048 blocks
//    for this size, per Guideline 11) -> deeper per-wave MLP.
//  - __builtin_nontemporal_load/store (nt flag) on the streamed buffers:
//    no reuse, keep 67 MB of stream-out from churning L2.

#define Z_LEVEL 25
#define TPB 256
#define UNROLL 8

typedef float f32x4 __attribute__((ext_vector_type(4)));

__device__ __forceinline__ float level_of(int l) {
    // numpy: levels = arange(25, f32) * f32(2.0/24.0) + (-1.0f), mul/add
    // separately rounded (no fma contraction -> use _rn intrinsics).
    const float step = (float)(2.0 / 24.0);
    return __fadd_rn(__fmul_rn((float)l, step), -1.0f);
}

__device__ __forceinline__ float dist2(float x, int l) {
    float t = __fsub_rn(x, level_of(l));
    return __fmul_rn(t, t);
}

__device__ __forceinline__ float hard_quant(float x) {
    // Candidate nearest index (approximate is fine; window of 3 covers it).
    float t = fmaf(x, 12.0f, 12.0f);          // (x + 1) * 12
    int c = __float2int_rn(t);
    c = max(0, min(Z_LEVEL - 1, c));
    int l0 = max(0, c - 1);
    int l2 = min(Z_LEVEL - 1, c + 1);

    // numpy argmin semantics: scan ascending index, replace only if
    // strictly less -> lowest index wins ties.
    float d0 = dist2(x, l0);
    float d1 = dist2(x, c);
    float d2 = dist2(x, l2);

    int best = l0;
    float db = d0;
    if (d1 < db) { db = d1; best = c; }
    if (d2 < db) { best = l2; }
    return level_of(best);
}

__device__ __forceinline__ f32x4 quant4(f32x4 v) {
    f32x4 r;
    r.x = hard_quant(v.x);
    r.y = hard_quant(v.y);
    r.z = hard_quant(v.z);
    r.w = hard_quant(v.w);
    return r;
}

__global__ void __launch_bounds__(TPB) quant_kernel(const f32x4* __restrict__ in,
                                                    f32x4* __restrict__ out,
                                                    int n4,
                                                    const float* __restrict__ in_s,
                                                    float* __restrict__ out_s,
                                                    int rem_base, int rem) {
    // Block-chunked layout: block b owns f4-range [b*2048, (b+1)*2048),
    // thread t touches t, t+256, ..., t+7*256 — every access fully coalesced.
    int base = blockIdx.x * (TPB * UNROLL) + threadIdx.x;

    if (base + (UNROLL - 1) * TPB < n4) {
        // Fast path: issue all 8 loads before any use -> 8 vmem ops in
        // flight per lane, latency fully overlapped.
        f32x4 v[UNROLL];
#pragma unroll
        for (int k = 0; k < UNROLL; ++k)
            v[k] = __builtin_nontemporal_load(&in[base + k * TPB]);
#pragma unroll
        for (int k = 0; k < UNROLL; ++k)
            __builtin_nontemporal_store(quant4(v[k]), &out[base + k * TPB]);
    } else {
        // Tail block only.
#pragma unroll
        for (int k = 0; k < UNROLL; ++k) {
            int i = base + k * TPB;
            if (i < n4) {
                f32x4 t = __builtin_nontemporal_load(&in[i]);
                __builtin_nontemporal_store(quant4(t), &out[i]);
            }
        }
    }

    // Scalar tail (n not divisible by 4) — rem <= 3, handled by one thread.
    if (base == 0 && rem > 0) {
        for (int k = 0; k < rem; ++k)
            out_s[rem_base + k] = hard_quant(in_s[rem_base + k]);
    }
}

extern "C" void kernel_launch(void* const* d_in, const int* in_sizes, int n_in,
                              void* d_out, int out_size, void* d_ws, size_t ws_size,
                              hipStream_t stream) {
    const float* x = (const float*)d_in[0];
    float* out = (float*)d_out;
    int n = in_sizes[0];
    int n4 = n >> 2;
    int rem = n & 3;
    int rem_base = n4 << 2;
    const int per_block = TPB * UNROLL;       // 2048 float4 per block
    int blocks = (n4 + per_block - 1) / per_block;
    if (blocks < 1) blocks = 1;
    quant_kernel<<<blocks, TPB, 0, stream>>>((const f32x4*)x, (f32x4*)out,
                                             n4, x, out, rem_base, rem);
}

// Round 2
// 108.863 us; speedup vs baseline: 1.0541x; 1.0541x over previous
//
#include <hip/hip_runtime.h>

// Quantizer forward: out = hard_q = nearest of 25 uniform levels in [-1, 1].
// (soft_q + stop_grad(hard_q - soft_q) has forward value == hard_q up to
//  ~1e-8 float rounding, far below the 2e-2 absmax threshold.)
//
// Correctness-critical: must match numpy's argmin over fl((x - levels[l])^2)
// with first-tie-wins. We pick a rounded candidate c, then re-decide among
// {c-1, c, c+1} using bit-exact numpy float32 arithmetic.
//
// R2: REVERT to R0 structure. R1 (UNROLL=8 + nontemporal hints) regressed
// the kernel ~26->30 us: nt loads forfeit L3 residual hits on the 64 MiB
// input, and extra MLP had no upside (BW already saturated at 8 waves/SIMD
// TLP). This simple 1-float4/thread version measured 108.5-109.4 us total,
// with the kernel at ~26 us vs a 21.3 us mixed-stream floor — the remaining
// ~83 us of the metric is harness re-poison fill traffic (2 x 256 MiB
// write-only at ~80% HBM peak), not controllable from this kernel.

#define Z_LEVEL 25

__device__ __forceinline__ float level_of(int l) {
    // numpy: levels = arange(25, f32) * f32(2.0/24.0) + (-1.0f), mul/add
    // separately rounded (no fma contraction -> use _rn intrinsics).
    const float step = (float)(2.0 / 24.0);
    return __fadd_rn(__fmul_rn((float)l, step), -1.0f);
}

__device__ __forceinline__ float dist2(float x, int l) {
    float t = __fsub_rn(x, level_of(l));
    return __fmul_rn(t, t);
}

__device__ __forceinline__ float hard_quant(float x) {
    // Candidate nearest index (approximate is fine; window of 3 covers it).
    float t = fmaf(x, 12.0f, 12.0f);          // (x + 1) * 12
    int c = __float2int_rn(t);
    c = max(0, min(Z_LEVEL - 1, c));
    int l0 = max(0, c - 1);
    int l2 = min(Z_LEVEL - 1, c + 1);

    // numpy argmin semantics: scan ascending index, replace only if
    // strictly less -> lowest index wins ties.
    float d0 = dist2(x, l0);
    float d1 = dist2(x, c);
    float d2 = dist2(x, l2);

    int best = l0;
    float db = d0;
    if (d1 < db) { db = d1; best = c; }
    if (d2 < db) { best = l2; }
    return level_of(best);
}

__global__ void __launch_bounds__(256) quant_kernel(const float4* __restrict__ in,
                                                    float4* __restrict__ out,
                                                    int n4,
                                                    const float* __restrict__ in_s,
                                                    float* __restrict__ out_s,
                                                    int rem_base, int rem) {
    int i = blockIdx.x * blockDim.x + threadIdx.x;
    if (i < n4) {
        float4 v = in[i];
        float4 r;
        r.x = hard_quant(v.x);
        r.y = hard_quant(v.y);
        r.z = hard_quant(v.z);
        r.w = hard_quant(v.w);
        out[i] = r;
    }
    // Scalar tail (n not divisible by 4) — rem <= 3, handled by one thread.
    if (i == 0 && rem > 0) {
        for (int k = 0; k < rem; ++k)
            out_s[rem_base + k] = hard_quant(in_s[rem_base + k]);
    }
}

extern "C" void kernel_launch(void* const* d_in, const int* in_sizes, int n_in,
                              void* d_out, int out_size, void* d_ws, size_t ws_size,
                              hipStream_t stream) {
    const float* x = (const float*)d_in[0];
    float* out = (float*)d_out;
    int n = in_sizes[0];
    int n4 = n >> 2;
    int rem = n & 3;
    int rem_base = n4 << 2;
    int blocks = (n4 + 255) / 256;
    if (blocks < 1) blocks = 1;
    quant_kernel<<<blocks, 256, 0, stream>>>((const float4*)x, (float4*)out,
                                             n4, x, out, rem_base, rem);
}